// Round 1
// 236.422 us; speedup vs baseline: 1.0357x; 1.0357x over previous
//
#include <hip/hip_runtime.h>
#include <hip/hip_bf16.h>

#define B_   8
#define N_   2048
#define FIN  128
#define OUTD 256
#define H_   4
#define LOG2E 1.44269504088896340736f

typedef __bf16 bf16x8 __attribute__((ext_vector_type(8)));
typedef float  f32x4  __attribute__((ext_vector_type(4)));

// ---------------- kernel 1: fp32 -> bf16 for X and W ----------------
__global__ __launch_bounds__(256) void conv_bf16(const float* __restrict__ X,
                                                 const float* __restrict__ W,
                                                 unsigned short* __restrict__ Xb,
                                                 unsigned short* __restrict__ Wb) {
    const int NX4 = (B_ * N_ * FIN) / 4;   // 524288 float4 groups in X
    int i = blockIdx.x * 256 + threadIdx.x;
    const float4* src;
    ushort4* dst;
    int idx;
    if (i < NX4) { src = (const float4*)X; dst = (ushort4*)Xb; idx = i; }
    else         { src = (const float4*)W; dst = (ushort4*)Wb; idx = i - NX4; }
    float4 v = src[idx];
    __hip_bfloat16 b0 = __float2bfloat16(v.x);
    __hip_bfloat16 b1 = __float2bfloat16(v.y);
    __hip_bfloat16 b2 = __float2bfloat16(v.z);
    __hip_bfloat16 b3 = __float2bfloat16(v.w);
    ushort4 o;
    o.x = *(unsigned short*)&b0;
    o.y = *(unsigned short*)&b1;
    o.z = *(unsigned short*)&b2;
    o.w = *(unsigned short*)&b3;
    dst[idx] = o;
}

// ---------------- kernel 2: X_trans = X @ W.T via bf16 MFMA ----------------
// grid (1024, 4), block 256 (4 waves). Each wave: one 16x16 output tile.
__global__ __launch_bounds__(256) void gemm_bf16(const unsigned short* __restrict__ Xb,
                                                 const unsigned short* __restrict__ Wb,
                                                 float* __restrict__ Xt) {
    int r0   = blockIdx.x * 16;                 // row tile
    int wave = threadIdx.x >> 6;
    int lane = threadIdx.x & 63;
    int c0   = (blockIdx.y * 4 + wave) * 16;    // channel tile
    int m = lane & 15, q = lane >> 4;

    const bf16x8* Arow = (const bf16x8*)(Xb + (size_t)(r0 + m) * FIN);
    const bf16x8* Brow = (const bf16x8*)(Wb + (size_t)(c0 + m) * FIN);
    f32x4 acc = {0.f, 0.f, 0.f, 0.f};
#pragma unroll
    for (int kc = 0; kc < 4; ++kc) {            // K = 128 = 4 x 32
        bf16x8 af = Arow[kc * 4 + q];
        bf16x8 bf = Brow[kc * 4 + q];
        acc = __builtin_amdgcn_mfma_f32_16x16x32_bf16(af, bf, acc, 0, 0, 0);
    }
    float* outp = Xt + (size_t)(r0 + q * 4) * OUTD + c0 + m;
#pragma unroll
    for (int reg = 0; reg < 4; ++reg)
        outp[(size_t)reg * OUTD] = acc[reg];
}

// ---------------- kernel 3: s,t = einsum('bnhd,hd->bnh'), pre-scaled by log2(e) ----
// Vectorized: one wave per row, each lane holds a float4 (whole 256-wide row
// covered by 64 lanes). Head h = lane>>4. 4-step shfl_xor reduce per 16-lane group.
__global__ __launch_bounds__(256) void st_kernel(const float* __restrict__ Xt,
                                                 const float* __restrict__ a_src,
                                                 const float* __restrict__ a_dst,
                                                 float* __restrict__ s_arr,
                                                 float* __restrict__ t_arr) {
    int row  = blockIdx.x * 4 + (threadIdx.x >> 6);
    int lane = threadIdx.x & 63;
    f32x4 v  = ((const f32x4*)(Xt + (size_t)row * OUTD))[lane];
    f32x4 as = ((const f32x4*)a_src)[lane];   // (H,D) row-major = 256 floats, same layout
    f32x4 ad = ((const f32x4*)a_dst)[lane];

    float vs = fmaf(v[0], as[0], fmaf(v[1], as[1], fmaf(v[2], as[2], v[3] * as[3])));
    float vd = fmaf(v[0], ad[0], fmaf(v[1], ad[1], fmaf(v[2], ad[2], v[3] * ad[3])));
#pragma unroll
    for (int off = 1; off < 16; off <<= 1) {
        vs += __shfl_xor(vs, off);
        vd += __shfl_xor(vd, off);
    }
    if ((lane & 15) == 0) {
        int h = lane >> 4;
        s_arr[(size_t)row * H_ + h] = vs * LOG2E;
        t_arr[(size_t)row * H_ + h] = vd * LOG2E;
    }
}

// ---------------- kernel 4: masked-softmax diagonal + output scale ----------------
// grid 1024 (= 8 b * 128 row-tiles), block 256. 16 rows/block, 16 lanes per row.
// LDS: t' for the whole graph b (2048x4 fp32 = 32 KB) -> 4 blocks/CU.
__global__ __launch_bounds__(256) void gat_main(const float* __restrict__ A,
                                                const float* __restrict__ s_arr,
                                                const float* __restrict__ t_arr,
                                                float* __restrict__ out) {
    __shared__ float t_lds[N_ * H_];            // 32 KB
    __shared__ float diag_lds[16][H_];

    int b  = blockIdx.x >> 7;
    int rt = blockIdx.x & 127;
    int r0 = rt * 16;
    int tid = threadIdx.x;

    // stage t' table for graph b
    {
        const float4* tsrc = (const float4*)(t_arr + (size_t)b * N_ * H_);
        float4* tdst = (float4*)t_lds;
#pragma unroll
        for (int i = 0; i < (N_ * H_) / 4 / 256; ++i)
            tdst[tid + i * 256] = tsrc[tid + i * 256];
    }
    __syncthreads();

    int r  = tid >> 4;          // 0..15 row within tile
    int lj = tid & 15;          // 16 lanes sweep j
    int gi = r0 + r;            // row index within graph b

    f32x4 s4 = *(const f32x4*)(s_arr + ((size_t)b * N_ + gi) * H_);
    const float* Arow = A + ((size_t)b * N_ + gi) * N_;

    f32x4 acc = {0.f, 0.f, 0.f, 0.f};

    auto body = [&](float4 a4, int it) {
        int j = it * 64 + lj * 4;
#pragma unroll
        for (int jj = 0; jj < 4; ++jj) {
            f32x4 t4 = ((const f32x4*)t_lds)[j + jj];
            float aj = (jj == 0) ? a4.x : (jj == 1) ? a4.y : (jj == 2) ? a4.z : a4.w;
#pragma unroll
            for (int h = 0; h < H_; ++h) {
                float y = s4[h] + t4[h];
                y = fmaxf(y, 0.2f * y);                      // leaky_relu (y pre-scaled by log2e)
                acc[h] = fmaf(aj, __builtin_amdgcn_exp2f(y), acc[h]);
            }
        }
    };

    // software-pipelined A stream: load it+1 before computing it
    float4 a4 = *(const float4*)(Arow + lj * 4);
    for (int it = 0; it < 31; ++it) {
        float4 a4n = *(const float4*)(Arow + (it + 1) * 64 + lj * 4);
        body(a4, it);
        a4 = a4n;
    }
    body(a4, 31);

    // reduce across the 16 lanes of this row
#pragma unroll
    for (int mk = 8; mk > 0; mk >>= 1) {
        acc[0] += __shfl_xor(acc[0], mk);
        acc[1] += __shfl_xor(acc[1], mk);
        acc[2] += __shfl_xor(acc[2], mk);
        acc[3] += __shfl_xor(acc[3], mk);
    }
    if (lj == 0) {
        f32x4 ti = ((const f32x4*)t_lds)[gi];
#pragma unroll
        for (int h = 0; h < H_; ++h) {
            float y = s4[h] + ti[h];
            y = fmaxf(y, 0.2f * y);
            diag_lds[r][h] = __builtin_amdgcn_exp2f(y) / acc[h];
        }
    }
    __syncthreads();

    // epilogue: out = diag * X_trans (in place; X_trans lives in d_out)
    float* orow = out + ((size_t)b * N_ + gi) * OUTD;
#pragma unroll
    for (int ii = 0; ii < 4; ++ii) {
        int c = lj * 4 + ii * 64;               // head h == ii (lj*4 < 64)
        float4 v = *(float4*)(orow + c);
        float dg = diag_lds[r][ii];
        v.x *= dg; v.y *= dg; v.z *= dg; v.w *= dg;
        *(float4*)(orow + c) = v;
    }
}

extern "C" void kernel_launch(void* const* d_in, const int* in_sizes, int n_in,
                              void* d_out, int out_size, void* d_ws, size_t ws_size,
                              hipStream_t stream) {
    const float* A     = (const float*)d_in[0];
    const float* X     = (const float*)d_in[1];
    const float* W     = (const float*)d_in[2];
    const float* a_src = (const float*)d_in[3];
    const float* a_dst = (const float*)d_in[4];
    float* out = (float*)d_out;

    // workspace carve-up (~4.8 MB total)
    char* ws = (char*)d_ws;
    unsigned short* Xb = (unsigned short*)ws;                 // 4,194,304 B
    unsigned short* Wb = (unsigned short*)(ws + 4194304);     //    65,536 B
    float* s_arr = (float*)(ws + 4259840);                    //   262,144 B
    float* t_arr = (float*)(ws + 4521984);                    //   262,144 B

    // 1) cast X, W to bf16
    conv_bf16<<<2080, 256, 0, stream>>>(X, W, Xb, Wb);
    // 2) X_trans = X @ W.T  (written into d_out, scaled in place later)
    gemm_bf16<<<dim3(1024, 4), 256, 0, stream>>>(Xb, Wb, out);
    // 3) attention source/dest logits (pre-scaled by log2 e)
    st_kernel<<<4096, 256, 0, stream>>>(out, a_src, a_dst, s_arr, t_arr);
    // 4) masked softmax diagonal + scale
    gat_main<<<1024, 256, 0, stream>>>(A, s_arr, t_arr, out);
}

// Round 2
// 234.145 us; speedup vs baseline: 1.0457x; 1.0097x over previous
//
#include <hip/hip_runtime.h>
#include <hip/hip_bf16.h>

#define B_   8
#define N_   2048
#define FIN  128
#define OUTD 256
#define H_   4
#define LOG2E 1.44269504088896340736f

typedef __bf16 bf16x8 __attribute__((ext_vector_type(8)));
typedef float  f32x4  __attribute__((ext_vector_type(4)));

__device__ inline __bf16 cvt1(float f) {
    __hip_bfloat16 b = __float2bfloat16(f);   // RNE, same as old conv_bf16
    return *reinterpret_cast<__bf16*>(&b);
}

// ---------------- kernel 1: fused convert + GEMM + s/t logits ----------------
// grid 1024 (one 16-row panel of the flattened (B*N) rows), block 256 = 4 waves.
// Wave w computes head h=w's 16x64 slice: 4 column-tiles x (K=128 = 4 x MFMA k32).
// fp32 X/W are loaded directly and converted to bf16 in registers (no conv pass).
// s,t = einsum('bnhd,hd->bnh') computed from the accumulators in-register
// (4 FMAs per row-reg + 16-lane shfl_xor reduce), pre-scaled by log2(e).
__global__ __launch_bounds__(256) void gemm_st(const float* __restrict__ X,
                                               const float* __restrict__ W,
                                               const float* __restrict__ a_src,
                                               const float* __restrict__ a_dst,
                                               float* __restrict__ Xt,
                                               float* __restrict__ s_arr,
                                               float* __restrict__ t_arr) {
    int r0   = blockIdx.x * 16;                 // row panel
    int h    = threadIdx.x >> 6;                // wave index == head index
    int lane = threadIdx.x & 63;
    int m = lane & 15, q = lane >> 4;

    const float* Arow = X + (size_t)(r0 + m) * FIN + q * 8;
    f32x4 acc[4] = {{0,0,0,0},{0,0,0,0},{0,0,0,0},{0,0,0,0}};

#pragma unroll
    for (int kc = 0; kc < 4; ++kc) {            // K = 128 = 4 x 32
        // A fragment: A[m][k=q*8+j] at k-offset kc*32
        float4 alo = *(const float4*)(Arow + kc * 32);
        float4 ahi = *(const float4*)(Arow + kc * 32 + 4);
        bf16x8 af;
        af[0] = cvt1(alo.x); af[1] = cvt1(alo.y); af[2] = cvt1(alo.z); af[3] = cvt1(alo.w);
        af[4] = cvt1(ahi.x); af[5] = cvt1(ahi.y); af[6] = cvt1(ahi.z); af[7] = cvt1(ahi.w);
#pragma unroll
        for (int ct = 0; ct < 4; ++ct) {        // 4 column tiles = 64 channels = head h
            // B fragment: B[k=q*8+j][n=m] = W[c0+m][k], c0 = h*64 + ct*16
            const float* Wrow = W + (size_t)(h * 64 + ct * 16 + m) * FIN + q * 8 + kc * 32;
            float4 blo = *(const float4*)(Wrow);
            float4 bhi = *(const float4*)(Wrow + 4);
            bf16x8 bf;
            bf[0] = cvt1(blo.x); bf[1] = cvt1(blo.y); bf[2] = cvt1(blo.z); bf[3] = cvt1(blo.w);
            bf[4] = cvt1(bhi.x); bf[5] = cvt1(bhi.y); bf[6] = cvt1(bhi.z); bf[7] = cvt1(bhi.w);
            acc[ct] = __builtin_amdgcn_mfma_f32_16x16x32_bf16(af, bf, acc[ct], 0, 0, 0);
        }
    }

    // write Xt: acc[ct] element (row = q*4+reg, col = h*64 + ct*16 + m)
#pragma unroll
    for (int ct = 0; ct < 4; ++ct) {
        float* outp = Xt + (size_t)(r0 + q * 4) * OUTD + h * 64 + ct * 16 + m;
#pragma unroll
        for (int reg = 0; reg < 4; ++reg)
            outp[(size_t)reg * OUTD] = acc[ct][reg];
    }

    // s/t logits for head h, rows r0 + q*4 + reg
    float sp[4] = {0, 0, 0, 0}, tp[4] = {0, 0, 0, 0};
#pragma unroll
    for (int ct = 0; ct < 4; ++ct) {
        float as = a_src[h * 64 + ct * 16 + m];
        float ad = a_dst[h * 64 + ct * 16 + m];
#pragma unroll
        for (int reg = 0; reg < 4; ++reg) {
            sp[reg] = fmaf(acc[ct][reg], as, sp[reg]);
            tp[reg] = fmaf(acc[ct][reg], ad, tp[reg]);
        }
    }
#pragma unroll
    for (int off = 1; off < 16; off <<= 1) {
#pragma unroll
        for (int reg = 0; reg < 4; ++reg) {
            sp[reg] += __shfl_xor(sp[reg], off);
            tp[reg] += __shfl_xor(tp[reg], off);
        }
    }
    if (m == 0) {
#pragma unroll
        for (int reg = 0; reg < 4; ++reg) {
            size_t row = (size_t)(r0 + q * 4 + reg);
            s_arr[row * H_ + h] = sp[reg] * LOG2E;
            t_arr[row * H_ + h] = tp[reg] * LOG2E;
        }
    }
}

// ---------------- kernel 2: masked-softmax diagonal + output scale ----------------
// grid 1024 (= 8 b * 128 row-tiles), block 256. 16 rows/block, 16 lanes per row.
// LDS: t' for the whole graph b (2048x4 fp32 = 32 KB) -> 4 blocks/CU.
__global__ __launch_bounds__(256) void gat_main(const float* __restrict__ A,
                                                const float* __restrict__ s_arr,
                                                const float* __restrict__ t_arr,
                                                float* __restrict__ out) {
    __shared__ float t_lds[N_ * H_];            // 32 KB
    __shared__ float diag_lds[16][H_];

    int b  = blockIdx.x >> 7;
    int rt = blockIdx.x & 127;
    int r0 = rt * 16;
    int tid = threadIdx.x;

    // stage t' table for graph b
    {
        const float4* tsrc = (const float4*)(t_arr + (size_t)b * N_ * H_);
        float4* tdst = (float4*)t_lds;
#pragma unroll
        for (int i = 0; i < (N_ * H_) / 4 / 256; ++i)
            tdst[tid + i * 256] = tsrc[tid + i * 256];
    }
    __syncthreads();

    int r  = tid >> 4;          // 0..15 row within tile
    int lj = tid & 15;          // 16 lanes sweep j
    int gi = r0 + r;            // row index within graph b

    f32x4 s4 = *(const f32x4*)(s_arr + ((size_t)b * N_ + gi) * H_);
    const float* Arow = A + ((size_t)b * N_ + gi) * N_;

    f32x4 acc = {0.f, 0.f, 0.f, 0.f};

    auto body = [&](float4 a4, int it) {
        int j = it * 64 + lj * 4;
#pragma unroll
        for (int jj = 0; jj < 4; ++jj) {
            f32x4 t4 = ((const f32x4*)t_lds)[j + jj];
            float aj = (jj == 0) ? a4.x : (jj == 1) ? a4.y : (jj == 2) ? a4.z : a4.w;
#pragma unroll
            for (int hh = 0; hh < H_; ++hh) {
                float y = s4[hh] + t4[hh];
                y = fmaxf(y, 0.2f * y);                      // leaky_relu (y pre-scaled by log2e)
                acc[hh] = fmaf(aj, __builtin_amdgcn_exp2f(y), acc[hh]);
            }
        }
    };

    // software-pipelined A stream: load it+1 before computing it
    float4 a4 = *(const float4*)(Arow + lj * 4);
    for (int it = 0; it < 31; ++it) {
        float4 a4n = *(const float4*)(Arow + (it + 1) * 64 + lj * 4);
        body(a4, it);
        a4 = a4n;
    }
    body(a4, 31);

    // reduce across the 16 lanes of this row
#pragma unroll
    for (int mk = 8; mk > 0; mk >>= 1) {
        acc[0] += __shfl_xor(acc[0], mk);
        acc[1] += __shfl_xor(acc[1], mk);
        acc[2] += __shfl_xor(acc[2], mk);
        acc[3] += __shfl_xor(acc[3], mk);
    }
    if (lj == 0) {
        f32x4 ti = ((const f32x4*)t_lds)[gi];
#pragma unroll
        for (int hh = 0; hh < H_; ++hh) {
            float y = s4[hh] + ti[hh];
            y = fmaxf(y, 0.2f * y);
            diag_lds[r][hh] = __builtin_amdgcn_exp2f(y) / acc[hh];
        }
    }
    __syncthreads();

    // epilogue: out = diag * X_trans (in place; X_trans lives in d_out)
    float* orow = out + ((size_t)b * N_ + gi) * OUTD;
#pragma unroll
    for (int ii = 0; ii < 4; ++ii) {
        int c = lj * 4 + ii * 64;               // head h == ii (lj*4 < 64)
        float4 v = *(float4*)(orow + c);
        float dg = diag_lds[r][ii];
        v.x *= dg; v.y *= dg; v.z *= dg; v.w *= dg;
        *(float4*)(orow + c) = v;
    }
}

extern "C" void kernel_launch(void* const* d_in, const int* in_sizes, int n_in,
                              void* d_out, int out_size, void* d_ws, size_t ws_size,
                              hipStream_t stream) {
    const float* A     = (const float*)d_in[0];
    const float* X     = (const float*)d_in[1];
    const float* W     = (const float*)d_in[2];
    const float* a_src = (const float*)d_in[3];
    const float* a_dst = (const float*)d_in[4];
    float* out = (float*)d_out;

    // workspace carve-up (s/t logits only now)
    char* ws = (char*)d_ws;
    float* s_arr = (float*)ws;                                //   262,144 B
    float* t_arr = (float*)(ws + 262144);                     //   262,144 B

    // 1) fused: convert + X@W.T (into d_out) + s/t logits
    gemm_st<<<1024, 256, 0, stream>>>(X, W, a_src, a_dst, out, s_arr, t_arr);
    // 2) masked softmax diagonal + scale
    gat_main<<<1024, 256, 0, stream>>>(A, s_arr, t_arr, out);
}